// Round 8
// baseline (225.430 us; speedup 1.0000x reference)
//
#include <hip/hip_runtime.h>
#include <hip/hip_bf16.h>
#include <math.h>

// Problem constants (from reference setup_inputs)
#define BATCH 8
#define SEQ   1536
#define DIM   1024
#define SEQ2  (2*SEQ)          // 3072
#define TEMP_INV 20.0f         // 1 / 0.05
// feats stored as fp8 e4m3 pre-scaled by 8 => sim accumulator carries 64x
#define EXP_SCALE (TEMP_INV / 64.0f)   // 0.3125

// GEMM tiling
#define BM 128
#define BN 128
#define BK 128                          // fp8 elements per K-tile (128 B/row)
#define KITERS (DIM/BK)                 // 8
#define TILES  (SEQ2 / BM)              // 24
#define NPAIRS (TILES * (TILES+1) / 2)  // 300 upper-triangular tile pairs

typedef int   i32x4 __attribute__((ext_vector_type(4)));
typedef int   i32x8 __attribute__((ext_vector_type(8)));
typedef float f32x4 __attribute__((ext_vector_type(4)));

#define GLOBAL_AS __attribute__((address_space(1)))
#define LDS_AS    __attribute__((address_space(3)))

__device__ inline void async_ld16(const void* g, void* lds_uniform) {
    // gfx950: direct global->LDS, 16B/lane; LDS dest = wave-uniform base + lane*16
    __builtin_amdgcn_global_load_lds((const GLOBAL_AS void*)g, (LDS_AS void*)lds_uniform, 16, 0, 0);
}

__device__ inline float wave_red64(float v) {
    #pragma unroll
    for (int m = 32; m > 0; m >>= 1) v += __shfl_xor(v, m, 64);
    return v;
}

// ---------------------------------------------------------------------------
// Kernel 1: L2-normalize both views -> fp8 e4m3 feats (x8 pre-scale)
// [B][2S][D]; fp32 pos cosine (exact, pre-quantization); zero-init Ng.
// One WAVE per token: no barriers.
// ---------------------------------------------------------------------------
__global__ __launch_bounds__(256) void normalize_kernel(
        const float* __restrict__ h1, const float* __restrict__ h2,
        unsigned char* __restrict__ feats, float* __restrict__ pos_cos,
        float* __restrict__ Ng) {
    int w = threadIdx.x >> 6, lane = threadIdx.x & 63;
    int tok = blockIdx.x * 4 + w;                 // 0 .. B*S-1
    int b = tok / SEQ, s = tok - b * SEQ;

    const float4* a4 = (const float4*)(h1 + (size_t)tok * DIM);
    const float4* b4 = (const float4*)(h2 + (size_t)tok * DIM);
    float4 av[4], bv[4];
    #pragma unroll
    for (int it = 0; it < 4; it++) { av[it] = a4[lane + 64*it]; bv[it] = b4[lane + 64*it]; }

    float ss1 = 0.f, ss2 = 0.f, sd = 0.f;
    #pragma unroll
    for (int it = 0; it < 4; it++) {
        ss1 += av[it].x*av[it].x + av[it].y*av[it].y + av[it].z*av[it].z + av[it].w*av[it].w;
        ss2 += bv[it].x*bv[it].x + bv[it].y*bv[it].y + bv[it].z*bv[it].z + bv[it].w*bv[it].w;
        sd  += av[it].x*bv[it].x + av[it].y*bv[it].y + av[it].z*bv[it].z + av[it].w*bv[it].w;
    }
    ss1 = wave_red64(ss1); ss2 = wave_red64(ss2); sd = wave_red64(sd);

    float sc1 = 1.0f / fmaxf(sqrtf(ss1), 1e-12f);
    float sc2 = 1.0f / fmaxf(sqrtf(ss2), 1e-12f);
    float s18 = sc1 * 8.0f, s28 = sc2 * 8.0f;   // x8: keep fp8 values normal

    unsigned int* f1row = (unsigned int*)(feats + ((size_t)b * SEQ2 + s) * DIM);
    unsigned int* f2row = (unsigned int*)(feats + ((size_t)b * SEQ2 + SEQ + s) * DIM);
    #pragma unroll
    for (int it = 0; it < 4; it++) {
        int p1 = __builtin_amdgcn_cvt_pk_fp8_f32(av[it].x * s18, av[it].y * s18, 0, 0);
        p1     = __builtin_amdgcn_cvt_pk_fp8_f32(av[it].z * s18, av[it].w * s18, p1, 1);
        int p2 = __builtin_amdgcn_cvt_pk_fp8_f32(bv[it].x * s28, bv[it].y * s28, 0, 0);
        p2     = __builtin_amdgcn_cvt_pk_fp8_f32(bv[it].z * s28, bv[it].w * s28, p2, 1);
        f1row[lane + 64*it] = (unsigned int)p1;
        f2row[lane + 64*it] = (unsigned int)p2;
    }
    if (lane == 0) {
        pos_cos[tok] = sd * sc1 * sc2;
        Ng[2*tok] = 0.0f;
        Ng[2*tok + 1] = 0.0f;
    }
}

// ---------------------------------------------------------------------------
// Kernel 2: symmetric fused sim-GEMM + exp + neg-mask, MX-fp8 K=128,
// WAVE-PRIVATE staging: ZERO __syncthreads in the kernel.
// Each wave DMAs its own 64-row A and B stripes (8 KB each) into its private
// 16 KB LDS region and waits only on its own vmcnt.  Per iter:
//   vmcnt(0) -> ds_read frags -> lgkmcnt(0) -> issue next DMA -> 16 MFMAs
// so the DMA flight overlaps the MFMAs, and 8 independent wave-streams/CU
// (2 blocks x 4 waves @ 64 KB LDS) self-overlap with no lock-step barrier.
// LDS swizzle (R4/R7 zero-conflict): chunk c of row r at slot c ^ (r&7).
// ---------------------------------------------------------------------------
__global__ __launch_bounds__(256) void gemm_ng_kernel(
        const unsigned char* __restrict__ feats, const int* __restrict__ mask,
        float* __restrict__ Ng) {
    int b = blockIdx.z;
    // decode triangular pair index -> (ti, tj), ti <= tj
    int p = blockIdx.x;
    int ti = 0;
    while (p >= TILES - ti) { p -= TILES - ti; ti++; }
    int tj = ti + p;
    int ibase = ti * BM, jbase = tj * BN;
    bool isdiag = (ti == tj);

    const unsigned char* fb = feats + (size_t)b * SEQ2 * DIM;

    __shared__ __align__(16) unsigned char lds[4][16384];   // 64 KB, wave-private

    int t = threadIdx.x;
    int lane = t & 63, w = t >> 6;
    int wrow = w >> 1, wcol = w & 1;       // 2x2 waves -> 64x64 each
    int colq = lane & 15, quad = lane >> 4;

    unsigned char* myA = &lds[w][0];
    unsigned char* myB = &lds[w][8192];

    // DMA inst q covers 8 rows (8 x 128 B = 1 KB): lane -> row 8q + (lane>>3),
    // stored slot lane&7, so logical source chunk = (lane&7) ^ ((lane>>3)&7).
    int lr = lane >> 3;                    // 0..7
    int sc = (lane & 7) ^ lr;              // swizzled source chunk
    const unsigned char* pa = fb + (size_t)(ibase + wrow * 64 + lr) * DIM + sc * 16;
    const unsigned char* pb = fb + (size_t)(jbase + wcol * 64 + lr) * DIM + sc * 16;

    auto stage = [&](int kb) {
        #pragma unroll
        for (int q = 0; q < 8; q++) {
            async_ld16(pa + (size_t)q * 8 * DIM + kb, myA + q * 1024);
            async_ld16(pb + (size_t)q * 8 * DIM + kb, myB + q * 1024);
        }
    };

    f32x4 acc[4][4] = {};
    // swizzled byte offsets of the two 16B chunks holding k = quad*32..+31
    int s0 = ((2 * quad)     ^ (colq & 7)) * 16;
    int s1 = ((2 * quad + 1) ^ (colq & 7)) * 16;

    stage(0);

    #pragma unroll 1
    for (int it = 0; it < KITERS; it++) {
        asm volatile("s_waitcnt vmcnt(0)" ::: "memory");   // my own DMAs only

        i32x8 af[4], bg[4];
        #pragma unroll
        for (int mi = 0; mi < 4; mi++) {
            int row = mi * 16 + colq;                      // row&7 == colq&7
            i32x4 lo = *(const i32x4*)(myA + row * 128 + s0);
            i32x4 hi = *(const i32x4*)(myA + row * 128 + s1);
            af[mi] = __builtin_shufflevector(lo, hi, 0, 1, 2, 3, 4, 5, 6, 7);
        }
        #pragma unroll
        for (int nj = 0; nj < 4; nj++) {
            int row = nj * 16 + colq;
            i32x4 lo = *(const i32x4*)(myB + row * 128 + s0);
            i32x4 hi = *(const i32x4*)(myB + row * 128 + s1);
            bg[nj] = __builtin_shufflevector(lo, hi, 0, 1, 2, 3, 4, 5, 6, 7);
        }
        // frags now in regs; LDS free for next iter's DMA, which overlaps MFMA
        asm volatile("s_waitcnt lgkmcnt(0)" ::: "memory");
        if (it + 1 < KITERS) stage((it + 1) * BK);

        #pragma unroll
        for (int mi = 0; mi < 4; mi++)
            #pragma unroll
            for (int nj = 0; nj < 4; nj++)
                acc[mi][nj] = __builtin_amdgcn_mfma_scale_f32_16x16x128_f8f6f4(
                    af[mi], bg[nj], acc[mi][nj],
                    0, 0,                       // cbsz=fp8, blgp=fp8
                    0, 0x7F7F7F7F,              // opselA, scaleA = 2^0
                    0, 0x7F7F7F7F);             // opselB, scaleB = 2^0
    }

    // Epilogue.  C/D layout: col = colq, row = quad*4 + reg.
    // Masks read straight from global (tiny, L1/L2-resident).
    const int* mb = mask + b * SEQ;
    float mj[4]; int jglob[4];
    #pragma unroll
    for (int nj = 0; nj < 4; nj++) {
        int j = jbase + wcol * 64 + nj * 16 + colq;
        int jm = (j < SEQ) ? j : j - SEQ;
        mj[nj] = mb[jm] ? 1.0f : 0.0f;
        jglob[nj] = j;
    }
    float colsum[4] = {0.f, 0.f, 0.f, 0.f};

    #pragma unroll
    for (int mi = 0; mi < 4; mi++) {
        int il0 = wrow * 64 + mi * 16 + quad * 4;
        float rsum[4] = {0.f, 0.f, 0.f, 0.f};
        float mr[4];
        #pragma unroll
        for (int r = 0; r < 4; r++) {
            int i = ibase + il0 + r;
            int im = (i < SEQ) ? i : i - SEQ;
            mr[r] = mb[im] ? 1.0f : 0.0f;
        }
        #pragma unroll
        for (int nj = 0; nj < 4; nj++) {
            #pragma unroll
            for (int r = 0; r < 4; r++) {
                int d = (ibase + il0 + r) - jglob[nj];
                bool same = (d == 0) | (d == SEQ) | (d == -SEQ);
                float e = same ? 0.0f : __expf(acc[mi][nj][r] * EXP_SCALE);
                rsum[r] += e * mj[nj];
                colsum[nj] += e * mr[r];
            }
        }
        // reduce each row sum across the 16 column lanes
        #pragma unroll
        for (int r = 0; r < 4; r++) {
            float v = rsum[r];
            #pragma unroll
            for (int m = 1; m < 16; m <<= 1) v += __shfl_xor(v, m, 64);
            if (colq == 0)
                atomicAdd(&Ng[b * SEQ2 + ibase + il0 + r], v);
        }
    }

    if (!isdiag) {
        // reduce col sums across the 4 quads
        #pragma unroll
        for (int nj = 0; nj < 4; nj++) {
            float v = colsum[nj];
            v += __shfl_xor(v, 16, 64);
            v += __shfl_xor(v, 32, 64);
            if (quad == 0)
                atomicAdd(&Ng[b * SEQ2 + jglob[nj]], v);
        }
    }
}

// ---------------------------------------------------------------------------
// Kernel 3: per-batch masked mean of per-token loss.
// per_tok[i] = log1p(Ng[i] * exp(-pos_sim/T))
// ---------------------------------------------------------------------------
__global__ __launch_bounds__(256) void loss_kernel(
        const float* __restrict__ Ng, const float* __restrict__ pos_cos,
        const int* __restrict__ mask, float* __restrict__ per_sample) {
    int b = blockIdx.x, t = threadIdx.x;
    float sum = 0.f, cnt = 0.f;
    for (int i = t; i < SEQ2; i += 256) {
        int im = (i < SEQ) ? i : i - SEQ;
        if (mask[b * SEQ + im]) {
            float ps = pos_cos[b * SEQ + im] * TEMP_INV;
            float ng = Ng[b * SEQ2 + i];
            sum += log1pf(ng * __expf(-ps));
            cnt += 1.0f;
        }
    }
    sum = wave_red64(sum); cnt = wave_red64(cnt);
    __shared__ float rs[4], rc[4];
    int lane = t & 63, w = t >> 6;
    if (lane == 0) { rs[w] = sum; rc[w] = cnt; }
    __syncthreads();
    if (t == 0) {
        float s = rs[0]+rs[1]+rs[2]+rs[3];
        float c = rc[0]+rc[1]+rc[2]+rc[3];
        per_sample[b] = s / c;
    }
}

__global__ void final_kernel(const float* __restrict__ per_sample, float* __restrict__ out) {
    if (threadIdx.x == 0) {
        float s = 0.f;
        #pragma unroll
        for (int b = 0; b < BATCH; b++) s += per_sample[b];
        out[0] = s / (float)BATCH;
    }
}

// ---------------------------------------------------------------------------
extern "C" void kernel_launch(void* const* d_in, const int* in_sizes, int n_in,
                              void* d_out, int out_size, void* d_ws, size_t ws_size,
                              hipStream_t stream) {
    const float* h1  = (const float*)d_in[0];
    const float* h2  = (const float*)d_in[1];
    const int* mask  = (const int*)d_in[2];
    float* out       = (float*)d_out;

    char* ws = (char*)d_ws;
    size_t feats_bytes = (size_t)BATCH * SEQ2 * DIM;          // 25,165,824 (fp8)
    unsigned char* feats = (unsigned char*)ws;
    float* pos_cos    = (float*)(ws + feats_bytes);
    float* Ng         = (float*)(ws + feats_bytes + (size_t)BATCH * SEQ * 4);
    float* per_sample = (float*)(ws + feats_bytes + (size_t)BATCH * SEQ * 4
                                 + (size_t)BATCH * SEQ2 * 4);

    normalize_kernel<<<BATCH * SEQ / 4, 256, 0, stream>>>(h1, h2, feats, pos_cos, Ng);

    dim3 g2(NPAIRS, 1, BATCH);
    gemm_ng_kernel<<<g2, 256, 0, stream>>>(feats, mask, Ng);

    loss_kernel<<<BATCH, 256, 0, stream>>>(Ng, pos_cos, mask, per_sample);
    final_kernel<<<1, 64, 0, stream>>>(per_sample, out);
}

// Round 9
// 210.730 us; speedup vs baseline: 1.0698x; 1.0698x over previous
//
#include <hip/hip_runtime.h>
#include <hip/hip_bf16.h>
#include <math.h>

// Problem constants (from reference setup_inputs)
#define BATCH 8
#define SEQ   1536
#define DIM   1024
#define SEQ2  (2*SEQ)          // 3072
#define TEMP_INV 20.0f         // 1 / 0.05
// feats stored as fp8 e4m3 pre-scaled by 8 => sim accumulator carries 64x
#define EXP_SCALE (TEMP_INV / 64.0f)   // 0.3125

// GEMM tiling
#define BM 128
#define BN 128
#define BK 128                          // fp8 elements per K-tile (128 B/row)
#define KITERS (DIM/BK)                 // 8
#define TILES  (SEQ2 / BM)              // 24
#define NPAIRS (TILES * (TILES+1) / 2)  // 300 upper-triangular tile pairs

typedef int   i32x4 __attribute__((ext_vector_type(4)));
typedef int   i32x8 __attribute__((ext_vector_type(8)));
typedef float f32x4 __attribute__((ext_vector_type(4)));

#define GLOBAL_AS __attribute__((address_space(1)))
#define LDS_AS    __attribute__((address_space(3)))

__device__ inline void async_ld16(const void* g, void* lds_uniform) {
    // gfx950: direct global->LDS, 16B/lane; LDS dest = wave-uniform base + lane*16
    __builtin_amdgcn_global_load_lds((const GLOBAL_AS void*)g, (LDS_AS void*)lds_uniform, 16, 0, 0);
}

__device__ inline float wave_red64(float v) {
    #pragma unroll
    for (int m = 32; m > 0; m >>= 1) v += __shfl_xor(v, m, 64);
    return v;
}

// ---------------------------------------------------------------------------
// Kernel 1: L2-normalize both views -> fp8 e4m3 feats (x8 pre-scale)
// [B][2S][D]; fp32 pos cosine (exact, pre-quantization); zero-init Ng.
// One WAVE per token: no barriers.
// ---------------------------------------------------------------------------
__global__ __launch_bounds__(256) void normalize_kernel(
        const float* __restrict__ h1, const float* __restrict__ h2,
        unsigned char* __restrict__ feats, float* __restrict__ pos_cos,
        float* __restrict__ Ng) {
    int w = threadIdx.x >> 6, lane = threadIdx.x & 63;
    int tok = blockIdx.x * 4 + w;                 // 0 .. B*S-1
    int b = tok / SEQ, s = tok - b * SEQ;

    const float4* a4 = (const float4*)(h1 + (size_t)tok * DIM);
    const float4* b4 = (const float4*)(h2 + (size_t)tok * DIM);
    float4 av[4], bv[4];
    #pragma unroll
    for (int it = 0; it < 4; it++) { av[it] = a4[lane + 64*it]; bv[it] = b4[lane + 64*it]; }

    float ss1 = 0.f, ss2 = 0.f, sd = 0.f;
    #pragma unroll
    for (int it = 0; it < 4; it++) {
        ss1 += av[it].x*av[it].x + av[it].y*av[it].y + av[it].z*av[it].z + av[it].w*av[it].w;
        ss2 += bv[it].x*bv[it].x + bv[it].y*bv[it].y + bv[it].z*bv[it].z + bv[it].w*bv[it].w;
        sd  += av[it].x*bv[it].x + av[it].y*bv[it].y + av[it].z*bv[it].z + av[it].w*bv[it].w;
    }
    ss1 = wave_red64(ss1); ss2 = wave_red64(ss2); sd = wave_red64(sd);

    float sc1 = 1.0f / fmaxf(sqrtf(ss1), 1e-12f);
    float sc2 = 1.0f / fmaxf(sqrtf(ss2), 1e-12f);
    float s18 = sc1 * 8.0f, s28 = sc2 * 8.0f;   // x8: keep fp8 values normal

    unsigned int* f1row = (unsigned int*)(feats + ((size_t)b * SEQ2 + s) * DIM);
    unsigned int* f2row = (unsigned int*)(feats + ((size_t)b * SEQ2 + SEQ + s) * DIM);
    #pragma unroll
    for (int it = 0; it < 4; it++) {
        int p1 = __builtin_amdgcn_cvt_pk_fp8_f32(av[it].x * s18, av[it].y * s18, 0, 0);
        p1     = __builtin_amdgcn_cvt_pk_fp8_f32(av[it].z * s18, av[it].w * s18, p1, 1);
        int p2 = __builtin_amdgcn_cvt_pk_fp8_f32(bv[it].x * s28, bv[it].y * s28, 0, 0);
        p2     = __builtin_amdgcn_cvt_pk_fp8_f32(bv[it].z * s28, bv[it].w * s28, p2, 1);
        f1row[lane + 64*it] = (unsigned int)p1;
        f2row[lane + 64*it] = (unsigned int)p2;
    }
    if (lane == 0) {
        pos_cos[tok] = sd * sc1 * sc2;
        Ng[2*tok] = 0.0f;
        Ng[2*tok + 1] = 0.0f;
    }
}

// ---------------------------------------------------------------------------
// Kernel 2: symmetric fused sim-GEMM + exp + neg-mask, MX-fp8 K=128.
// R7 structure (block-coop staging, 8 K-iters) + XCD-BATCH LOCALITY:
// 1-D grid of 2400; workgroup->XCD assignment round-robins by linear block
// id (%8, measured m09), so decoding batch = bid&7 pins all 300 blocks of a
// batch to one XCD -- whose 4 MB L2 holds that batch's entire 3 MB feats.
// Staging DMAs become ~200-cyc L2 hits instead of ~500-900-cyc L3/HBM trips.
// (Perf heuristic only: wrong mapping costs speed, never correctness.)
// LDS swizzle (R4/R7 zero-conflict): chunk c of row r at slot c ^ (r&7).
// ---------------------------------------------------------------------------
__global__ __launch_bounds__(256) void gemm_ng_kernel(
        const unsigned char* __restrict__ feats, const int* __restrict__ mask,
        float* __restrict__ Ng) {
    int bid = blockIdx.x;
    int b = bid & 7;                 // XCD-local batch
    int p = bid >> 3;                // 0..299 triangular pair index
    int ti = 0;
    while (p >= TILES - ti) { p -= TILES - ti; ti++; }
    int tj = ti + p;
    int ibase = ti * BM, jbase = tj * BN;
    bool isdiag = (ti == tj);

    const unsigned char* fb = feats + (size_t)b * SEQ2 * DIM;

    __shared__ __align__(16) unsigned char As[BM][BK];  // 16 KB
    __shared__ __align__(16) unsigned char Bs[BN][BK];  // 16 KB
    __shared__ float mrow_s[BM];
    __shared__ float mcol_s[BN];

    int t = threadIdx.x;
    int lane = t & 63, w = t >> 6;
    int wrow = w >> 1, wcol = w & 1;       // 2x2 waves -> 64x64 each
    int colq = lane & 15, quad = lane >> 4;

    // stage masks (as float) for the tile's rows/cols
    if (t < BM) {
        int i = ibase + t; int im = (i < SEQ) ? i : i - SEQ;
        mrow_s[t] = mask[b * SEQ + im] ? 1.0f : 0.0f;
    } else {
        int j = jbase + (t - BM); int jm = (j < SEQ) ? j : j - SEQ;
        mcol_s[t - BM] = mask[b * SEQ + jm] ? 1.0f : 0.0f;
    }

    // Staging: per issue (4 KB = 32 rows x 128 B), thread t covers row
    // sr = t>>3, stored slot t&7 -> logical source chunk (t&7) ^ (sr&7).
    int sr = t >> 3;
    int sc = (t & 7) ^ (sr & 7);
    const unsigned char* a0 = fb + (size_t)(ibase + sr) * DIM + sc * 16;
    const unsigned char* b0 = fb + (size_t)(jbase + sr) * DIM + sc * 16;

    f32x4 acc[4][4] = {};
    // swizzled byte offsets of the two 16B chunks holding k = quad*32..+31
    int s0 = ((2 * quad)     ^ (colq & 7)) * 16;
    int s1 = ((2 * quad + 1) ^ (colq & 7)) * 16;

    for (int it = 0; it < KITERS; it++) {
        __syncthreads();                    // LDS reuse from previous iter
        size_t kb = (size_t)it * BK;        // byte offset along k
        #pragma unroll
        for (int q = 0; q < 4; q++) {       // 32 rows per issue
            async_ld16(a0 + (size_t)q * 32 * DIM + kb, (char*)&As[0][0] + q * 4096 + w * 1024);
            async_ld16(b0 + (size_t)q * 32 * DIM + kb, (char*)&Bs[0][0] + q * 4096 + w * 1024);
        }
        asm volatile("s_waitcnt vmcnt(0)" ::: "memory");
        __syncthreads();

        i32x8 af[4], bg[4];
        #pragma unroll
        for (int mi = 0; mi < 4; mi++) {
            int row = wrow * 64 + mi * 16 + colq;   // row&7 == colq&7
            i32x4 lo = *(const i32x4*)&As[row][s0];
            i32x4 hi = *(const i32x4*)&As[row][s1];
            af[mi] = __builtin_shufflevector(lo, hi, 0, 1, 2, 3, 4, 5, 6, 7);
        }
        #pragma unroll
        for (int nj = 0; nj < 4; nj++) {
            int row = wcol * 64 + nj * 16 + colq;
            i32x4 lo = *(const i32x4*)&Bs[row][s0];
            i32x4 hi = *(const i32x4*)&Bs[row][s1];
            bg[nj] = __builtin_shufflevector(lo, hi, 0, 1, 2, 3, 4, 5, 6, 7);
        }

        #pragma unroll
        for (int mi = 0; mi < 4; mi++)
            #pragma unroll
            for (int nj = 0; nj < 4; nj++)
                acc[mi][nj] = __builtin_amdgcn_mfma_scale_f32_16x16x128_f8f6f4(
                    af[mi], bg[nj], acc[mi][nj],
                    0, 0,                       // cbsz=fp8, blgp=fp8
                    0, 0x7F7F7F7F,              // opselA, scaleA = 2^0
                    0, 0x7F7F7F7F);             // opselB, scaleB = 2^0
    }

    // Epilogue.  C/D layout: col = colq, row = quad*4 + reg.
    float mj[4]; int jglob[4];
    #pragma unroll
    for (int nj = 0; nj < 4; nj++) {
        int jl = wcol * 64 + nj * 16 + colq;
        mj[nj] = mcol_s[jl];
        jglob[nj] = jbase + jl;
    }
    float colsum[4] = {0.f, 0.f, 0.f, 0.f};

    #pragma unroll
    for (int mi = 0; mi < 4; mi++) {
        int il0 = wrow * 64 + mi * 16 + quad * 4;
        float rsum[4] = {0.f, 0.f, 0.f, 0.f};
        float mr[4];
        #pragma unroll
        for (int r = 0; r < 4; r++) mr[r] = mrow_s[il0 + r];
        #pragma unroll
        for (int nj = 0; nj < 4; nj++) {
            #pragma unroll
            for (int r = 0; r < 4; r++) {
                int d = (ibase + il0 + r) - jglob[nj];
                bool same = (d == 0) | (d == SEQ) | (d == -SEQ);
                float e = same ? 0.0f : __expf(acc[mi][nj][r] * EXP_SCALE);
                rsum[r] += e * mj[nj];
                colsum[nj] += e * mr[r];
            }
        }
        // reduce each row sum across the 16 column lanes
        #pragma unroll
        for (int r = 0; r < 4; r++) {
            float v = rsum[r];
            #pragma unroll
            for (int m = 1; m < 16; m <<= 1) v += __shfl_xor(v, m, 64);
            if (colq == 0)
                atomicAdd(&Ng[b * SEQ2 + ibase + il0 + r], v);
        }
    }

    if (!isdiag) {
        // reduce col sums across the 4 quads
        #pragma unroll
        for (int nj = 0; nj < 4; nj++) {
            float v = colsum[nj];
            v += __shfl_xor(v, 16, 64);
            v += __shfl_xor(v, 32, 64);
            if (quad == 0)
                atomicAdd(&Ng[b * SEQ2 + jglob[nj]], v);
        }
    }
}

// ---------------------------------------------------------------------------
// Kernel 3: per-batch masked mean of per-token loss.
// per_tok[i] = log1p(Ng[i] * exp(-pos_sim/T))
// ---------------------------------------------------------------------------
__global__ __launch_bounds__(256) void loss_kernel(
        const float* __restrict__ Ng, const float* __restrict__ pos_cos,
        const int* __restrict__ mask, float* __restrict__ per_sample) {
    int b = blockIdx.x, t = threadIdx.x;
    float sum = 0.f, cnt = 0.f;
    for (int i = t; i < SEQ2; i += 256) {
        int im = (i < SEQ) ? i : i - SEQ;
        if (mask[b * SEQ + im]) {
            float ps = pos_cos[b * SEQ + im] * TEMP_INV;
            float ng = Ng[b * SEQ2 + i];
            sum += log1pf(ng * __expf(-ps));
            cnt += 1.0f;
        }
    }
    sum = wave_red64(sum); cnt = wave_red64(cnt);
    __shared__ float rs[4], rc[4];
    int lane = t & 63, w = t >> 6;
    if (lane == 0) { rs[w] = sum; rc[w] = cnt; }
    __syncthreads();
    if (t == 0) {
        float s = rs[0]+rs[1]+rs[2]+rs[3];
        float c = rc[0]+rc[1]+rc[2]+rc[3];
        per_sample[b] = s / c;
    }
}

__global__ void final_kernel(const float* __restrict__ per_sample, float* __restrict__ out) {
    if (threadIdx.x == 0) {
        float s = 0.f;
        #pragma unroll
        for (int b = 0; b < BATCH; b++) s += per_sample[b];
        out[0] = s / (float)BATCH;
    }
}

// ---------------------------------------------------------------------------
extern "C" void kernel_launch(void* const* d_in, const int* in_sizes, int n_in,
                              void* d_out, int out_size, void* d_ws, size_t ws_size,
                              hipStream_t stream) {
    const float* h1  = (const float*)d_in[0];
    const float* h2  = (const float*)d_in[1];
    const int* mask  = (const int*)d_in[2];
    float* out       = (float*)d_out;

    char* ws = (char*)d_ws;
    size_t feats_bytes = (size_t)BATCH * SEQ2 * DIM;          // 25,165,824 (fp8)
    unsigned char* feats = (unsigned char*)ws;
    float* pos_cos    = (float*)(ws + feats_bytes);
    float* Ng         = (float*)(ws + feats_bytes + (size_t)BATCH * SEQ * 4);
    float* per_sample = (float*)(ws + feats_bytes + (size_t)BATCH * SEQ * 4
                                 + (size_t)BATCH * SEQ2 * 4);

    normalize_kernel<<<BATCH * SEQ / 4, 256, 0, stream>>>(h1, h2, feats, pos_cos, Ng);

    gemm_ng_kernel<<<NPAIRS * BATCH, 256, 0, stream>>>(feats, mask, Ng);

    loss_kernel<<<BATCH, 256, 0, stream>>>(Ng, pos_cos, mask, per_sample);
    final_kernel<<<1, 64, 0, stream>>>(per_sample, out);
}

// Round 10
// 209.083 us; speedup vs baseline: 1.0782x; 1.0079x over previous
//
#include <hip/hip_runtime.h>
#include <hip/hip_bf16.h>
#include <math.h>

// Problem constants (from reference setup_inputs)
#define BATCH 8
#define SEQ   1536
#define DIM   1024
#define SEQ2  (2*SEQ)          // 3072
#define TEMP_INV 20.0f         // 1 / 0.05
// feats stored as fp8 e4m3 pre-scaled by 8 => sim accumulator carries 64x
#define EXP_SCALE (TEMP_INV / 64.0f)   // 0.3125

// GEMM tiling
#define BM 128
#define BN 128
#define BK 128                          // fp8 elements per K-tile (128 B/row)
#define KITERS (DIM/BK)                 // 8
#define TILES  (SEQ2 / BM)              // 24
#define NPAIRS (TILES * (TILES+1) / 2)  // 300 upper-triangular tile pairs

typedef int   i32x4 __attribute__((ext_vector_type(4)));
typedef int   i32x8 __attribute__((ext_vector_type(8)));
typedef float f32x4 __attribute__((ext_vector_type(4)));

#define GLOBAL_AS __attribute__((address_space(1)))
#define LDS_AS    __attribute__((address_space(3)))

__device__ inline void async_ld16(const void* g, void* lds_uniform) {
    // gfx950: direct global->LDS, 16B/lane; LDS dest = wave-uniform base + lane*16
    __builtin_amdgcn_global_load_lds((const GLOBAL_AS void*)g, (LDS_AS void*)lds_uniform, 16, 0, 0);
}

__device__ inline float wave_red64(float v) {
    #pragma unroll
    for (int m = 32; m > 0; m >>= 1) v += __shfl_xor(v, m, 64);
    return v;
}

// ---------------------------------------------------------------------------
// Kernel 1: L2-normalize both views -> fp8 e4m3 feats (x8 pre-scale)
// [B][2S][D]; fp32 pos cosine (exact, pre-quantization); zero-init Ng and
// d_out (loss blocks atomicAdd into d_out later in the same stream).
// One WAVE per token: no barriers.
// ---------------------------------------------------------------------------
__global__ __launch_bounds__(256) void normalize_kernel(
        const float* __restrict__ h1, const float* __restrict__ h2,
        unsigned char* __restrict__ feats, float* __restrict__ pos_cos,
        float* __restrict__ Ng, float* __restrict__ out) {
    int w = threadIdx.x >> 6, lane = threadIdx.x & 63;
    int tok = blockIdx.x * 4 + w;                 // 0 .. B*S-1
    int b = tok / SEQ, s = tok - b * SEQ;

    const float4* a4 = (const float4*)(h1 + (size_t)tok * DIM);
    const float4* b4 = (const float4*)(h2 + (size_t)tok * DIM);
    float4 av[4], bv[4];
    #pragma unroll
    for (int it = 0; it < 4; it++) { av[it] = a4[lane + 64*it]; bv[it] = b4[lane + 64*it]; }

    float ss1 = 0.f, ss2 = 0.f, sd = 0.f;
    #pragma unroll
    for (int it = 0; it < 4; it++) {
        ss1 += av[it].x*av[it].x + av[it].y*av[it].y + av[it].z*av[it].z + av[it].w*av[it].w;
        ss2 += bv[it].x*bv[it].x + bv[it].y*bv[it].y + bv[it].z*bv[it].z + bv[it].w*bv[it].w;
        sd  += av[it].x*bv[it].x + av[it].y*bv[it].y + av[it].z*bv[it].z + av[it].w*bv[it].w;
    }
    ss1 = wave_red64(ss1); ss2 = wave_red64(ss2); sd = wave_red64(sd);

    float sc1 = 1.0f / fmaxf(sqrtf(ss1), 1e-12f);
    float sc2 = 1.0f / fmaxf(sqrtf(ss2), 1e-12f);
    float s18 = sc1 * 8.0f, s28 = sc2 * 8.0f;   // x8: keep fp8 values normal

    unsigned int* f1row = (unsigned int*)(feats + ((size_t)b * SEQ2 + s) * DIM);
    unsigned int* f2row = (unsigned int*)(feats + ((size_t)b * SEQ2 + SEQ + s) * DIM);
    #pragma unroll
    for (int it = 0; it < 4; it++) {
        int p1 = __builtin_amdgcn_cvt_pk_fp8_f32(av[it].x * s18, av[it].y * s18, 0, 0);
        p1     = __builtin_amdgcn_cvt_pk_fp8_f32(av[it].z * s18, av[it].w * s18, p1, 1);
        int p2 = __builtin_amdgcn_cvt_pk_fp8_f32(bv[it].x * s28, bv[it].y * s28, 0, 0);
        p2     = __builtin_amdgcn_cvt_pk_fp8_f32(bv[it].z * s28, bv[it].w * s28, p2, 1);
        f1row[lane + 64*it] = (unsigned int)p1;
        f2row[lane + 64*it] = (unsigned int)p2;
    }
    if (lane == 0) {
        pos_cos[tok] = sd * sc1 * sc2;
        Ng[2*tok] = 0.0f;
        Ng[2*tok + 1] = 0.0f;
        if (tok == 0) out[0] = 0.0f;   // loss blocks accumulate into out
    }
}

// ---------------------------------------------------------------------------
// Kernel 2: symmetric fused sim-GEMM + exp + neg-mask, MX-fp8 K=128.
// R9 structure (block-coop staging, XCD-batch pinning via bid&7) +
// PREFETCH-DISTANCE-1 DOUBLE BUFFER (R5 pattern):
//   sync (drains prev iter's DMA, which had a full read+MFMA stretch to fly)
//   -> read frags(buf) -> stage(it+1, buf^1) -> MFMA -> buf^=1
// One barrier per iter, no explicit waitcnt: the compiler's mandatory
// vmcnt(0)+lgkmcnt(0) before s_barrier provides exactly the needed drain.
// LDS swizzle (R4/R7 zero-conflict): chunk c of row r at slot c ^ (r&7).
// ---------------------------------------------------------------------------
__global__ __launch_bounds__(256) void gemm_ng_kernel(
        const unsigned char* __restrict__ feats, const int* __restrict__ mask,
        float* __restrict__ Ng) {
    int bid = blockIdx.x;
    int b = bid & 7;                 // XCD-local batch (m09: placement %8)
    int p = bid >> 3;                // 0..299 triangular pair index
    int ti = 0;
    while (p >= TILES - ti) { p -= TILES - ti; ti++; }
    int tj = ti + p;
    int ibase = ti * BM, jbase = tj * BN;
    bool isdiag = (ti == tj);

    const unsigned char* fb = feats + (size_t)b * SEQ2 * DIM;

    __shared__ __align__(16) unsigned char As[2][BM][BK];  // 2 x 16 KB
    __shared__ __align__(16) unsigned char Bs[2][BN][BK];  // 2 x 16 KB
    __shared__ float mrow_s[BM];
    __shared__ float mcol_s[BN];

    int t = threadIdx.x;
    int lane = t & 63, w = t >> 6;
    int wrow = w >> 1, wcol = w & 1;       // 2x2 waves -> 64x64 each
    int colq = lane & 15, quad = lane >> 4;

    // Staging: per issue (4 KB = 32 rows x 128 B), thread t covers row
    // sr = t>>3, stored slot t&7 -> logical source chunk (t&7) ^ (sr&7).
    int sr = t >> 3;
    int sc = (t & 7) ^ (sr & 7);
    const unsigned char* a0 = fb + (size_t)(ibase + sr) * DIM + sc * 16;
    const unsigned char* b0 = fb + (size_t)(jbase + sr) * DIM + sc * 16;

    auto stage = [&](int it, int buf) {
        size_t kb = (size_t)it * BK;
        #pragma unroll
        for (int q = 0; q < 4; q++) {       // 32 rows per issue
            async_ld16(a0 + (size_t)q * 32 * DIM + kb, (char*)&As[buf][0][0] + q * 4096 + w * 1024);
            async_ld16(b0 + (size_t)q * 32 * DIM + kb, (char*)&Bs[buf][0][0] + q * 4096 + w * 1024);
        }
    };

    stage(0, 0);                            // first DMA flies during mask setup

    // stage masks (as float) for the tile's rows/cols
    if (t < BM) {
        int i = ibase + t; int im = (i < SEQ) ? i : i - SEQ;
        mrow_s[t] = mask[b * SEQ + im] ? 1.0f : 0.0f;
    } else {
        int j = jbase + (t - BM); int jm = (j < SEQ) ? j : j - SEQ;
        mcol_s[t - BM] = mask[b * SEQ + jm] ? 1.0f : 0.0f;
    }

    f32x4 acc[4][4] = {};
    // swizzled byte offsets of the two 16B chunks holding k = quad*32..+31
    int s0 = ((2 * quad)     ^ (colq & 7)) * 16;
    int s1 = ((2 * quad + 1) ^ (colq & 7)) * 16;

    int buf = 0;
    #pragma unroll 1
    for (int it = 0; it < KITERS; it++) {
        __syncthreads();       // compiler-inserted vmcnt(0): drains buf's DMAs

        i32x8 af[4], bg[4];
        #pragma unroll
        for (int mi = 0; mi < 4; mi++) {
            int row = wrow * 64 + mi * 16 + colq;   // row&7 == colq&7
            i32x4 lo = *(const i32x4*)&As[buf][row][s0];
            i32x4 hi = *(const i32x4*)&As[buf][row][s1];
            af[mi] = __builtin_shufflevector(lo, hi, 0, 1, 2, 3, 4, 5, 6, 7);
        }
        #pragma unroll
        for (int nj = 0; nj < 4; nj++) {
            int row = wcol * 64 + nj * 16 + colq;
            i32x4 lo = *(const i32x4*)&Bs[buf][row][s0];
            i32x4 hi = *(const i32x4*)&Bs[buf][row][s1];
            bg[nj] = __builtin_shufflevector(lo, hi, 0, 1, 2, 3, 4, 5, 6, 7);
        }

        if (it + 1 < KITERS) stage(it + 1, buf ^ 1);   // flies across MFMAs

        #pragma unroll
        for (int mi = 0; mi < 4; mi++)
            #pragma unroll
            for (int nj = 0; nj < 4; nj++)
                acc[mi][nj] = __builtin_amdgcn_mfma_scale_f32_16x16x128_f8f6f4(
                    af[mi], bg[nj], acc[mi][nj],
                    0, 0,                       // cbsz=fp8, blgp=fp8
                    0, 0x7F7F7F7F,              // opselA, scaleA = 2^0
                    0, 0x7F7F7F7F);             // opselB, scaleB = 2^0
        buf ^= 1;
    }

    // Epilogue.  C/D layout: col = colq, row = quad*4 + reg.
    float mj[4]; int jglob[4];
    #pragma unroll
    for (int nj = 0; nj < 4; nj++) {
        int jl = wcol * 64 + nj * 16 + colq;
        mj[nj] = mcol_s[jl];
        jglob[nj] = jbase + jl;
    }
    float colsum[4] = {0.f, 0.f, 0.f, 0.f};

    #pragma unroll
    for (int mi = 0; mi < 4; mi++) {
        int il0 = wrow * 64 + mi * 16 + quad * 4;
        float rsum[4] = {0.f, 0.f, 0.f, 0.f};
        float mr[4];
        #pragma unroll
        for (int r = 0; r < 4; r++) mr[r] = mrow_s[il0 + r];
        #pragma unroll
        for (int nj = 0; nj < 4; nj++) {
            #pragma unroll
            for (int r = 0; r < 4; r++) {
                int d = (ibase + il0 + r) - jglob[nj];
                bool same = (d == 0) | (d == SEQ) | (d == -SEQ);
                float e = same ? 0.0f : __expf(acc[mi][nj][r] * EXP_SCALE);
                rsum[r] += e * mj[nj];
                colsum[nj] += e * mr[r];
            }
        }
        // reduce each row sum across the 16 column lanes
        #pragma unroll
        for (int r = 0; r < 4; r++) {
            float v = rsum[r];
            #pragma unroll
            for (int m = 1; m < 16; m <<= 1) v += __shfl_xor(v, m, 64);
            if (colq == 0)
                atomicAdd(&Ng[b * SEQ2 + ibase + il0 + r], v);
        }
    }

    if (!isdiag) {
        // reduce col sums across the 4 quads
        #pragma unroll
        for (int nj = 0; nj < 4; nj++) {
            float v = colsum[nj];
            v += __shfl_xor(v, 16, 64);
            v += __shfl_xor(v, 32, 64);
            if (quad == 0)
                atomicAdd(&Ng[b * SEQ2 + jglob[nj]], v);
        }
    }
}

// ---------------------------------------------------------------------------
// Kernel 3: per-batch masked mean of per-token loss, accumulated straight
// into out[0] (zero-inited by normalize; device-scope atomics are XCD-safe).
// per_tok[i] = log1p(Ng[i] * exp(-pos_sim/T))
// ---------------------------------------------------------------------------
__global__ __launch_bounds__(256) void loss_kernel(
        const float* __restrict__ Ng, const float* __restrict__ pos_cos,
        const int* __restrict__ mask, float* __restrict__ out) {
    int b = blockIdx.x, t = threadIdx.x;
    float sum = 0.f, cnt = 0.f;
    for (int i = t; i < SEQ2; i += 256) {
        int im = (i < SEQ) ? i : i - SEQ;
        if (mask[b * SEQ + im]) {
            float ps = pos_cos[b * SEQ + im] * TEMP_INV;
            float ng = Ng[b * SEQ2 + i];
            sum += log1pf(ng * __expf(-ps));
            cnt += 1.0f;
        }
    }
    sum = wave_red64(sum); cnt = wave_red64(cnt);
    __shared__ float rs[4], rc[4];
    int lane = t & 63, w = t >> 6;
    if (lane == 0) { rs[w] = sum; rc[w] = cnt; }
    __syncthreads();
    if (t == 0) {
        float s = rs[0]+rs[1]+rs[2]+rs[3];
        float c = rc[0]+rc[1]+rc[2]+rc[3];
        atomicAdd(out, s / c * (1.0f / BATCH));
    }
}

// ---------------------------------------------------------------------------
extern "C" void kernel_launch(void* const* d_in, const int* in_sizes, int n_in,
                              void* d_out, int out_size, void* d_ws, size_t ws_size,
                              hipStream_t stream) {
    const float* h1  = (const float*)d_in[0];
    const float* h2  = (const float*)d_in[1];
    const int* mask  = (const int*)d_in[2];
    float* out       = (float*)d_out;

    char* ws = (char*)d_ws;
    size_t feats_bytes = (size_t)BATCH * SEQ2 * DIM;          // 25,165,824 (fp8)
    unsigned char* feats = (unsigned char*)ws;
    float* pos_cos    = (float*)(ws + feats_bytes);
    float* Ng         = (float*)(ws + feats_bytes + (size_t)BATCH * SEQ * 4);

    normalize_kernel<<<BATCH * SEQ / 4, 256, 0, stream>>>(h1, h2, feats, pos_cos, Ng, out);

    gemm_ng_kernel<<<NPAIRS * BATCH, 256, 0, stream>>>(feats, mask, Ng);

    loss_kernel<<<BATCH, 256, 0, stream>>>(Ng, pos_cos, mask, out);
}